// Round 3
// baseline (438.656 us; speedup 1.0000x reference)
//
#include <hip/hip_runtime.h>
#include <hip/hip_bf16.h>

#define DEV __device__ __forceinline__

DEV float waveReduceMax(float x){
  #pragma unroll
  for(int o=32;o>0;o>>=1) x = fmaxf(x, __shfl_down(x,o,64));
  return x;
}
DEV float waveReduceSum(float x){
  #pragma unroll
  for(int o=32;o>0;o>>=1) x += __shfl_down(x,o,64);
  return x;
}
// 256-thread block helpers (4 waves). Pattern: sync, write, sync, read -> safe reuse.
DEV float blockMax256(float x, float* sc){
  int lane = threadIdx.x & 63, wid = threadIdx.x >> 6;
  x = waveReduceMax(x);
  __syncthreads();
  if(lane==0) sc[wid] = x;
  __syncthreads();
  return fmaxf(fmaxf(sc[0],sc[1]), fmaxf(sc[2],sc[3]));
}
DEV float blockSum256(float x, float* sc){
  int lane = threadIdx.x & 63, wid = threadIdx.x >> 6;
  x = waveReduceSum(x);
  __syncthreads();
  if(lane==0) sc[wid] = x;
  __syncthreads();
  return sc[0]+sc[1]+sc[2]+sc[3];
}
DEV float blockScan256(float x, float* sc, float& total){
  int lane = threadIdx.x & 63, wid = threadIdx.x >> 6;
  float v = x;
  #pragma unroll
  for(int o=1;o<64;o<<=1){ float t = __shfl_up(v,o,64); if(lane>=o) v += t; }
  __syncthreads();
  if(lane==63) sc[wid] = v;
  __syncthreads();
  float pre=0.f, tot=0.f;
  #pragma unroll
  for(int ww=0;ww<4;ww++){ float s = sc[ww]; tot += s; if(ww<wid) pre += s; }
  total = tot;
  return v + pre;
}
DEV float blockSum128(float x, float* sc){
  int lane = threadIdx.x & 63, wid = threadIdx.x >> 6;
  x = waveReduceSum(x);
  __syncthreads();
  if(lane==0) sc[wid] = x;
  __syncthreads();
  return sc[0]+sc[1];
}

// out[row, o] = bias[o] + sum_c in[row,c] * W[o,c]   (x @ W.T + b), all fp32
template<int R>
__global__ __launch_bounds__(128) void linear128(
  const float* __restrict__ in, const float* __restrict__ W, const float* __restrict__ bias,
  float* __restrict__ out, int nrows)
{
  __shared__ float sIn[R][128];
  int r0 = blockIdx.x * R;
  int c = threadIdx.x;
  #pragma unroll
  for(int r=0;r<R;r++){
    int row = r0 + r;
    sIn[r][c] = (row < nrows) ? in[row*128 + c] : 0.f;
  }
  __syncthreads();
  float acc[R];
  float bv = bias[c];
  #pragma unroll
  for(int r=0;r<R;r++) acc[r] = bv;
  const float4* Wr = (const float4*)(W + c*128);   // 128 f32 = 32 float4
  #pragma unroll
  for(int k=0;k<32;k++){
    float4 w = Wr[k];
    #pragma unroll
    for(int r=0;r<R;r++){
      const float* s = &sIn[r][k*4];
      acc[r] += w.x*s[0] + w.y*s[1] + w.z*s[2] + w.w*s[3];
    }
  }
  #pragma unroll
  for(int r=0;r<R;r++){
    int row = r0 + r;
    if(row < nrows) out[row*128 + c] = acc[r];
  }
}

DEV float dot16(const float* a, const float* b){
  float s = 0.f;
  #pragma unroll
  for(int k=0;k<16;k++) s += a[k]*b[k];
  return s;
}

// Layer-1 attention: one block per (b,h,i). mask j<=i, no maxout.
__global__ __launch_bounds__(256) void attn1_kernel(
  const float* __restrict__ qk, const float* __restrict__ v1,
  const float* __restrict__ gamma, float* __restrict__ qs, float* __restrict__ aout)
{
  __shared__ float sc4[4];
  __shared__ float ps[256];
  __shared__ float part[256];
  int i  = blockIdx.x & 255;
  int bh = blockIdx.x >> 8;      // b*8 + h
  int b = bh >> 3, h = bh & 7;
  int j = threadIdx.x;

  const float* qrow = qk + (b*256 + i)*128 + h*16;
  const float* krow = qk + (b*256 + j)*128 + h*16;
  float raw = dot16(qrow, krow) * 0.25f;   // / sqrt(16)
  bool valid = (j <= i);

  float m1 = blockMax256(valid ? raw : -3e38f, sc4);
  float e1 = valid ? __expf(raw - m1) : 0.f;
  float tot;
  float cum = blockScan256(e1, sc4, tot);
  float remn = fmaxf((tot - cum) / tot, 0.f);
  float pos  = fabsf((float)(j - i));
  float dist = sqrtf(remn * pos);
  float g = fabsf(gamma[h]);
  float eff = fminf(fmaxf(__expf(-g*dist), 1e-5f), 1e5f);
  float s2 = raw * eff;
  float m2 = blockMax256(valid ? s2 : -3e38f, sc4);
  float e2 = valid ? __expf(s2 - m2) : 0.f;
  float Z = blockSum256(e2, sc4);
  float pr = e2 / Z;

  qs[((size_t)(bh*256 + i))*256 + j] = pr;
  ps[j] = pr;
  __syncthreads();

  int d = j & 15, gq = j >> 4;
  const float* vb = v1 + (b*256 + gq*16)*128 + h*16 + d;
  float partial = 0.f;
  #pragma unroll
  for(int jj=0;jj<16;jj++) partial += ps[gq*16+jj] * vb[jj*128];
  part[gq*16 + d] = partial;
  __syncthreads();
  if(j < 16){
    float o = 0.f;
    #pragma unroll
    for(int g2=0; g2<16; g2++) o += part[g2*16 + j];
    aout[(b*256 + i)*128 + h*16 + j] = o;   // concat layout (b,i,h*16+d)
  }
}

// proj(Wo) + residual + LayerNorm -> p (fp32, row-major)
template<int R>
__global__ __launch_bounds__(128) void projresln_p(
  const float* __restrict__ cin, const float* __restrict__ Wo, const float* __restrict__ bo,
  const float* __restrict__ resid, const float* __restrict__ lng, const float* __restrict__ lnb,
  float* __restrict__ outp)
{
  __shared__ float sIn[R][128];
  __shared__ float sc[2];
  int r0 = blockIdx.x * R;
  int c = threadIdx.x;
  #pragma unroll
  for(int r=0;r<R;r++) sIn[r][c] = cin[(r0+r)*128 + c];
  __syncthreads();
  float x[R];
  float bv = bo[c];
  #pragma unroll
  for(int r=0;r<R;r++) x[r] = bv;
  const float4* Wr = (const float4*)(Wo + c*128);
  #pragma unroll
  for(int k=0;k<32;k++){
    float4 w = Wr[k];
    #pragma unroll
    for(int r=0;r<R;r++){
      const float* s = &sIn[r][k*4];
      x[r] += w.x*s[0] + w.y*s[1] + w.z*s[2] + w.w*s[3];
    }
  }
  #pragma unroll
  for(int r=0;r<R;r++) x[r] += resid[(r0+r)*128 + c];
  float g = lng[c], bb = lnb[c];
  for(int r=0;r<R;r++){
    float m  = blockSum128(x[r], sc) * 0.0078125f;
    float dd = x[r] - m;
    float var = blockSum128(dd*dd, sc) * 0.0078125f;
    outp[(r0+r)*128 + c] = dd * rsqrtf(var + 1e-5f) * g + bb;
  }
}

// proj(Wo) + residual(know) + LN -> z (fp32, layout (b, i, n, c))
template<int R>
__global__ __launch_bounds__(128) void projresln_z(
  const float* __restrict__ cin, const float* __restrict__ Wo, const float* __restrict__ bo,
  const float* __restrict__ know, const float* __restrict__ lng, const float* __restrict__ lnb,
  float* __restrict__ zout)
{
  __shared__ float sIn[R][128];
  __shared__ float sc[2];
  int r0 = blockIdx.x * R;
  int c = threadIdx.x;
  #pragma unroll
  for(int r=0;r<R;r++) sIn[r][c] = cin[(r0+r)*128 + c];
  __syncthreads();
  float x[R];
  float bv = bo[c];
  #pragma unroll
  for(int r=0;r<R;r++) x[r] = bv;
  const float4* Wr = (const float4*)(Wo + c*128);
  #pragma unroll
  for(int k=0;k<32;k++){
    float4 w = Wr[k];
    #pragma unroll
    for(int r=0;r<R;r++){
      const float* s = &sIn[r][k*4];
      x[r] += w.x*s[0] + w.y*s[1] + w.z*s[2] + w.w*s[3];
    }
  }
  float g = lng[c], bb = lnb[c];
  for(int r=0;r<R;r++){
    int row = r0 + r;                 // row = (b*16+n)*256 + i
    int n = (row >> 8) & 15;
    x[r] += know[n*128 + c];
    float m  = blockSum128(x[r], sc) * 0.0078125f;
    float dd = x[r] - m;
    float var = blockSum128(dd*dd, sc) * 0.0078125f;
    float y = dd * rsqrtf(var + 1e-5f) * g + bb;
    int b = row >> 12, i = row & 255;
    zout[(((size_t)(b*256 + i))*16 + n)*128 + c] = y;
  }
}

// Layer-4 precompute: raw[j] (i-independent) and prefix P[j] of exp(raw - M)
__global__ __launch_bounds__(256) void attn4_pre(
  const float* __restrict__ q4, const float* __restrict__ k4,
  float* __restrict__ raw4, float* __restrict__ P4)
{
  __shared__ float sc4[4];
  int bnh = blockIdx.x;                 // b*128 + n*8 + h
  int b = bnh >> 7, n = (bnh >> 3) & 15, h = bnh & 7;
  int j = threadIdx.x;
  const float* qrow = q4 + n*128 + h*16;
  const float* krow = k4 + (b*256 + j)*128 + h*16;
  float raw = dot16(qrow, krow) * 0.25f;
  float M = blockMax256(raw, sc4);
  float E = __expf(raw - M);
  float tot;
  float P = blockScan256(E, sc4, tot);
  raw4[bnh*256 + j] = raw;
  P4[bnh*256 + j]   = P;
}

// Layer-4 main: 16 rows per block. mask j<i (strict), maxout scale = min(Z,5).
__global__ __launch_bounds__(256) void attn4_main(
  const float* __restrict__ raw4, const float* __restrict__ P4,
  const float* __restrict__ v4, const float* __restrict__ gamma,
  float* __restrict__ ks, float* __restrict__ aout)
{
  __shared__ float sc4[4];
  __shared__ float rawL[256], PL[256], ps[256], part[256];
  __shared__ float vT[16*257];
  int tile = blockIdx.x & 15;
  int bnh  = blockIdx.x >> 4;
  int b = bnh >> 7, n = (bnh >> 3) & 15, h = bnh & 7;
  int t = threadIdx.x;

  rawL[t] = raw4[bnh*256 + t];
  PL[t]   = P4[bnh*256 + t];
  {
    const float* vr = v4 + (b*256 + t)*128 + h*16;
    #pragma unroll
    for(int dd=0; dd<16; dd++) vT[dd*257 + t] = vr[dd];
  }
  __syncthreads();

  float g4a = fabsf(gamma[h]);
  int d = t & 15, gq = t >> 4;
  size_t ksbase = ((size_t)(b*8 + h)*256)*(16*256) + (size_t)n*256;

  for(int r=0;r<16;r++){
    int i = tile*16 + r;
    float prs = 0.f;
    if(i > 0){                                   // i is block-uniform
      float Pm1 = PL[i-1];
      int jm = (t < i-1) ? t : (i-1);
      float cum = PL[jm] / Pm1;
      float remn = fmaxf(1.f - cum, 0.f);
      float pos  = fabsf((float)(t - i));
      float dist = sqrtf(remn * pos);
      float eff  = fminf(fmaxf(__expf(-g4a*dist), 1e-5f), 1e5f);
      float s2   = rawL[t] * eff;
      bool valid = (t < i);
      float m2 = blockMax256(valid ? s2 : -3e38f, sc4);
      float e2 = valid ? __expf(s2 - m2) : 0.f;
      float Z  = blockSum256(e2, sc4);
      prs = e2 * (fminf(Z, 5.f) / Z);            // maxout: max(p)=1/Z
    }
    ks[ksbase + (size_t)i*(16*256) + t] = prs;
    __syncthreads();
    ps[t] = prs;
    __syncthreads();
    float partial = 0.f;
    #pragma unroll
    for(int jj=0;jj<16;jj++) partial += ps[gq*16+jj] * vT[d*257 + gq*16 + jj];
    part[gq*16 + d] = partial;
    __syncthreads();
    if(t < 16){
      float o = 0.f;
      #pragma unroll
      for(int g2=0; g2<16; g2++) o += part[g2*16 + t];
      aout[((b*16 + n)*256 + i)*128 + h*16 + t] = o;
    }
    __syncthreads();
  }
}

extern "C" void kernel_launch(void* const* d_in, const int* in_sizes, int n_in,
                              void* d_out, int out_size, void* d_ws, size_t ws_size,
                              hipStream_t stream)
{
  (void)in_sizes; (void)n_in; (void)out_size; (void)ws_size;
  const float* q_emb   = (const float*)d_in[0];
  const float* s_emb   = (const float*)d_in[1];
  const float* b1_Wq   = (const float*)d_in[3];
  const float* b1_bq   = (const float*)d_in[4];
  const float* b1_Wv   = (const float*)d_in[5];
  const float* b1_bv   = (const float*)d_in[6];
  const float* b1_Wo   = (const float*)d_in[7];
  const float* b1_bo   = (const float*)d_in[8];
  const float* b1_gamma= (const float*)d_in[9];
  const float* b1_lng  = (const float*)d_in[10];
  const float* b1_lnb  = (const float*)d_in[11];
  const float* b4_Wq   = (const float*)d_in[12];
  const float* b4_bq   = (const float*)d_in[13];
  const float* b4_Wk   = (const float*)d_in[14];
  const float* b4_bk   = (const float*)d_in[15];
  const float* b4_Wv   = (const float*)d_in[16];
  const float* b4_bv   = (const float*)d_in[17];
  const float* b4_Wo   = (const float*)d_in[18];
  const float* b4_bo   = (const float*)d_in[19];
  const float* b4_gamma= (const float*)d_in[20];
  const float* b4_lng  = (const float*)d_in[21];
  const float* b4_lnb  = (const float*)d_in[22];
  const float* know    = (const float*)d_in[23];

  float* w    = (float*)d_ws;
  float* qk1  = w;                 // 131072  (B,S,128) q==k proj layer1
  float* v1   = w + 131072;        // 131072
  float* a1o  = w + 262144;        // 131072  attn1 concat out
  float* p    = w + 393216;        // 131072
  float* q4   = w + 524288;        // 2048    (16,128)
  float* k4   = w + 526336;        // 131072
  float* v4   = w + 657408;        // 131072
  float* raw4 = w + 788480;        // 131072  (512,256)
  float* P4   = w + 919552;        // 131072
  float* a4o  = w + 1050624;       // 2097152 attn4 concat out

  float* z_out  = (float*)d_out;                 // (4,256,2048)
  float* qs_out = z_out + 2097152;               // (4,8,256,256)
  float* ks_out = z_out + 4194304;               // (4,8,256,16,256)

  // Layer 1
  linear128<4><<<256,128,0,stream>>>(q_emb, b1_Wq, b1_bq, qk1, 1024);
  linear128<4><<<256,128,0,stream>>>(s_emb, b1_Wv, b1_bv, v1, 1024);
  attn1_kernel<<<8192,256,0,stream>>>(qk1, v1, b1_gamma, qs_out, a1o);
  projresln_p<8><<<128,128,0,stream>>>(a1o, b1_Wo, b1_bo, q_emb, b1_lng, b1_lnb, p);

  // Layer 4 projections
  linear128<4><<<256,128,0,stream>>>(q_emb, b4_Wk, b4_bk, k4, 1024);
  linear128<4><<<256,128,0,stream>>>(p, b4_Wv, b4_bv, v4, 1024);
  linear128<4><<<4,128,0,stream>>>(know, b4_Wq, b4_bq, q4, 16);

  // Layer 4 attention
  attn4_pre<<<512,256,0,stream>>>(q4, k4, raw4, P4);
  attn4_main<<<8192,256,0,stream>>>(raw4, P4, v4, b4_gamma, ks_out, a4o);

  // Output projection + LN -> z
  projresln_z<8><<<2048,128,0,stream>>>(a4o, b4_Wo, b4_bo, know, b4_lng, b4_lnb, z_out);
}